// Round 4
// baseline (828.695 us; speedup 1.0000x reference)
//
#include <hip/hip_runtime.h>

#define BN_EPS 1e-3f
#define NREP 16  // BN stat replicas

typedef __attribute__((ext_vector_type(8))) short short8;
typedef __attribute__((ext_vector_type(4))) float float4v;

__device__ __forceinline__ short f2bf(float f) {
    unsigned u = __float_as_uint(f);
    unsigned r = (u + 0x7FFFu + ((u >> 16) & 1u)) >> 16;
    return (short)r;
}

// s_waitcnt vmcnt(N) only
template <int N>
__device__ __forceinline__ void waitcnt_vm() {
    __builtin_amdgcn_s_waitcnt(0xF70 | (N & 15) | ((N >> 4) << 14));
}

// raw s_barrier (no compiler vmcnt(0) drain; we wait explicitly)
__device__ __forceinline__ void wave_barrier() { asm volatile("s_barrier" ::: "memory"); }

// async global -> LDS, 16B/lane; lds dst wave-uniform base + lane*16
__device__ __forceinline__ void dma16(const short* g, short* l) {
    __builtin_amdgcn_global_load_lds((const __attribute__((address_space(1))) void*)g,
                                     (__attribute__((address_space(3))) void*)l, 16, 0, 0);
}

// ---------------- small utility kernels ----------------

__global__ __launch_bounds__(256) void zero_kernel(float* p, int n) {
    int i = blockIdx.x * 256 + threadIdx.x;
    if (i < n) p[i] = 0.f;
}

__global__ __launch_bounds__(256) void copy_kernel(const float* __restrict__ in,
                                                   float* __restrict__ out, int n) {
    int i = blockIdx.x * 256 + threadIdx.x;
    if (i < n) out[i] = in[i];
}

__global__ __launch_bounds__(256) void zero_rows_kernel(short* a, short* b, long maxN) {
    int t = threadIdx.x;
    if (t < 32) a[maxN * 32 + t] = 0;
    else if (t < 96) a[maxN * 64 + (t - 32)] = 0;
    else if (t < 128) b[maxN * 32 + (t - 96)] = 0;
    else if (t < 192) b[maxN * 64 + (t - 128)] = 0;
}

__global__ __launch_bounds__(256) void xyz_kernel(const int* __restrict__ coords,
                                                  float* __restrict__ out, int N,
                                                  float sx, float sy, float sz) {
    int n = blockIdx.x * 256 + threadIdx.x;
    if (n >= N) return;
    int4 c = ((const int4*)coords)[n];
    out[n * 3 + 0] = c.w * sx;
    out[n * 3 + 1] = c.z * sy - 40.0f;
    out[n * 3 + 2] = c.y * sz - 3.0f;
}

__global__ __launch_bounds__(256) void convert_f0(const float* __restrict__ f,
                                                  short* __restrict__ dst, int N) {
    int i = blockIdx.x * 256 + threadIdx.x;
    if (i >= N * 32) return;
    int c = i & 31, n = i >> 5;
    dst[i] = (c < 4) ? f2bf(f[n * 4 + c]) : (short)0;
}

// ---- weight prep: W [K][CI][CO] fp32 -> Wt [K][c*CT+t][quad][l16][8] bf16 ----
struct PrepAll {
    const float* src[14];
    short* dst[14];
    int CI[14];
    int CO[14];
    int CHP[14];
    int cum[15];
};

__global__ __launch_bounds__(256) void prep_all_kernel(PrepAll d) {
    int i = blockIdx.x * 256 + threadIdx.x;
    if (i >= d.cum[14]) return;
    int l = 0;
    while (l < 13 && i >= d.cum[l + 1]) ++l;
    int f = i - d.cum[l];
    int CO = d.CO[l], CI = d.CI[l];
    int NCH = d.CHP[l] / 32, CT = CO / 16;
    int e = f & 7;
    int u = f >> 3;
    int l16 = u & 15;
    int q = (u >> 4) & 3;
    int u2 = u >> 6;
    int t = u2 % CT;
    int c = (u2 / CT) % NCH;
    int k = u2 / (CT * NCH);
    int ci = c * 32 + q * 8 + e;
    int co = t * 16 + l16;
    float v = (ci < CI) ? d.src[l][((size_t)k * CI + ci) * CO + co] : 0.f;
    d.dst[l][f] = f2bf(v);
}

// per-k A fragments for one wave (32 rows x CHP), held in VGPRs
struct ASet {
    short8 v0, v1, v2, v3;  // (mt0,c0) (mt0,c1) (mt1,c0) (mt1,c1)
};

// ---------------- hybrid MFMA sparse conv, split-K over taps ----------------
// grid = (row blocks, SPLITS). Each block handles taps [kbase, kbase+kn) and
// writes a PARTIAL preactivation into its split's buffer. Active-k compaction
// within the split. BN stats are computed later by reduce_stats (sum of
// partials is needed before squaring).
// A: direct global->VGPR gathers, depth-2 pipeline; B: 3-slot LDS ring.
template <int CHP, int CO, int KS>
__global__ __launch_bounds__(256, 4) void sconv_hyb(const short* __restrict__ feat,
                                                    const int* __restrict__ rb,
                                                    const short* __restrict__ Wt,
                                                    float* __restrict__ parts, long pstride,
                                                    int N, int zrow, int Ktot) {
    constexpr int NCH = CHP / 32;
    constexpr int CT = CO / 16;
    constexpr int BTILE = CO * CHP;    // shorts
    constexpr int NB = BTILE / 512;    // B DMA insts per tile (1KB each)
    constexpr int A = 2 * NCH;         // A loads per wave per tile
    constexpr int ROWS = 128;

    __shared__ __align__(16) short ldsB[3 * BTILE];
    __shared__ int sIdx[KS * ROWS];
    __shared__ int sFlag[KS];
    __shared__ int sKl[KS];
    __shared__ int sKn;

    const int tid = threadIdx.x;
    const int w = tid >> 6;
    const int lane = tid & 63;
    const int quad = lane >> 4;
    const int l16 = lane & 15;
    const int m0 = blockIdx.x * ROWS;
    const int kbase = blockIdx.y * KS;
    int kn = Ktot - kbase;
    if (kn > KS) kn = KS;
    float* __restrict__ out = parts + (size_t)blockIdx.y * pstride;

    if (tid < KS) sFlag[tid] = 0;
    __syncthreads();
    for (int e = tid; e < kn * ROWS; e += 256) {
        int r = m0 + (e & (ROWS - 1));
        int v = (r < N) ? rb[(size_t)(kbase + (e >> 7)) * N + r] : -1;
        sIdx[e] = v;
        if (v >= 0) sFlag[e >> 7] = 1;  // benign race: same value
    }
    __syncthreads();
    // wave 0: compact active (local) k list via ballot + prefix popcount
    if (w == 0) {
        int f = (lane < kn) ? sFlag[lane] : 0;
        unsigned long long m = __ballot(f != 0);
        if (f) sKl[__popcll(m & ((1ull << lane) - 1ull))] = lane;
        if (lane == 0) sKn = (int)__popcll(m);
    }
    __syncthreads();
    const int nk = sKn;

    const short* fquad = feat + quad * 8;

    auto issueB = [&](int kg, int slot) {  // kg = GLOBAL tap index
        const short* wk = Wt + (size_t)kg * BTILE + lane * 8;
        short* bb = ldsB + slot * BTILE;
#pragma unroll
        for (int jj = 0; jj < (NB + 3) / 4; ++jj) {
            int j = jj * 4 + w;
            if (j < NB) dma16(wk + j * 512, bb + j * 512);
        }
    };
    auto issueA = [&](int kp) {  // kp = LOCAL tap index (sIdx row)
        ASet s;
        int i0 = sIdx[kp * ROWS + w * 32 + l16];
        int i1 = sIdx[kp * ROWS + w * 32 + 16 + l16];
        const short* p0 = fquad + (size_t)(i0 < 0 ? zrow : i0) * CHP;
        const short* p1 = fquad + (size_t)(i1 < 0 ? zrow : i1) * CHP;
        s.v0 = *(const short8*)p0;
        s.v2 = *(const short8*)p1;
        if constexpr (NCH == 2) {
            s.v1 = *(const short8*)(p0 + 32);
            s.v3 = *(const short8*)(p1 + 32);
        } else {
            s.v1 = (short8)0;
            s.v3 = (short8)0;
        }
        return s;
    };

    float4v acc[2][CT];
#pragma unroll
    for (int mt = 0; mt < 2; ++mt)
#pragma unroll
        for (int t = 0; t < CT; ++t) acc[mt][t] = (float4v)0.f;

    // per-wave wait constant: own B share + own A loads (one tile's worth)
    constexpr int BW0 = NB / 4 + ((NB % 4) > 0 ? 1 : 0);
    constexpr int BW1 = NB / 4 + ((NB % 4) > 1 ? 1 : 0);
    constexpr int BW2 = NB / 4 + ((NB % 4) > 2 ? 1 : 0);
    constexpr int BW3 = NB / 4;

    // prologue: up to 2 active tiles in flight (order per tile: B then A)
    ASet sA{}, sB{}, sC{};
    if (nk > 0) {
        issueB(kbase + sKl[0], 0);
        sA = issueA(sKl[0]);
    }
    if (nk > 1) {
        issueB(kbase + sKl[1], 1);
        sB = issueA(sKl[1]);
    }

    int slotRd = 0, slotWr = 2;
    for (int i = 0; i < nk; ++i) {
        if (i < nk - 1) {
            if (w == 0) waitcnt_vm<BW0 + A>();
            else if (w == 1) waitcnt_vm<BW1 + A>();
            else if (w == 2) waitcnt_vm<BW2 + A>();
            else waitcnt_vm<BW3 + A>();
        } else {
            waitcnt_vm<0>();
        }
        __builtin_amdgcn_sched_barrier(0);
        wave_barrier();  // all waves' B(i) halves landed; all done reading slot i-1
        if (i + 2 < nk) {
            issueB(kbase + sKl[i + 2], slotWr);
            sC = issueA(sKl[i + 2]);
        }
        // compute tile i: B from LDS slot, A from sA registers
        const short* bb = ldsB + slotRd * BTILE;
#pragma unroll
        for (int c = 0; c < NCH; ++c) {
#pragma unroll
            for (int t = 0; t < CT; ++t) {
                short8 bf = *(const short8*)(bb + ((c * CT + t) * 64 + quad * 16 + l16) * 8);
#pragma unroll
                for (int mt = 0; mt < 2; ++mt) {
                    short8 af = (mt == 0) ? ((c == 0) ? sA.v0 : sA.v1)
                                          : ((c == 0) ? sA.v2 : sA.v3);
                    acc[mt][t] = __builtin_amdgcn_mfma_f32_16x16x32_bf16(af, bf, acc[mt][t], 0,
                                                                         0, 0);
                }
            }
        }
        sA = sB;
        sB = sC;
        slotRd = (slotRd == 2) ? 0 : slotRd + 1;
        slotWr = (slotWr == 2) ? 0 : slotWr + 1;
    }

    // stores: D layout col = lane&15, row = quad*4 + reg. All rows written
    // (zeros included) so the combine pass can sum partials unconditionally.
#pragma unroll
    for (int mt = 0; mt < 2; ++mt)
#pragma unroll
        for (int t = 0; t < CT; ++t) {
            int col = t * 16 + l16;
#pragma unroll
            for (int r = 0; r < 4; ++r) {
                int orow = m0 + w * 32 + mt * 16 + quad * 4 + r;
                if (orow < N) out[(size_t)orow * CO + col] = acc[mt][t][r];
            }
        }
}

// ---------------- combine partials + BN stats ----------------
// comb[n][c] = sum over splits of parts[s][n][c]; atomically accumulate
// per-channel sum / sumsq into replica stats. For SPLITS==1 the partial IS
// the final preact (no combine write; bn_apply reads parts directly).
template <int COUT, int SPLITS>
__global__ __launch_bounds__(256) void reduce_stats(const float* __restrict__ parts, long pstride,
                                                    float* __restrict__ comb,
                                                    float* __restrict__ stats, int N) {
    constexpr int RPP = 256 / COUT;  // rows per pass
    constexpr int NPASS = 8;
    int tid = threadIdx.x;
    int c = tid & (COUT - 1);
    int rl = tid / COUT;
    long base = (long)blockIdx.x * (NPASS * RPP) + rl;
    float s = 0.f, q = 0.f;
#pragma unroll
    for (int p = 0; p < NPASS; ++p) {
        long r = base + (long)p * RPP;
        if (r < N) {
            float v = parts[r * COUT + c];
            if (SPLITS > 1) {
#pragma unroll
                for (int sp = 1; sp < SPLITS; ++sp) v += parts[(size_t)sp * pstride + r * COUT + c];
                comb[r * COUT + c] = v;
            }
            s += v;
            q += v * v;
        }
    }
    __shared__ float sS[256];
    __shared__ float sQ[256];
    sS[tid] = s;
    sQ[tid] = q;
    __syncthreads();
#pragma unroll
    for (int off = 128; off >= COUT; off >>= 1) {
        if (tid < off) {
            sS[tid] += sS[tid + off];
            sQ[tid] += sQ[tid + off];
        }
        __syncthreads();
    }
    if (tid < COUT) {
        float* st = stats + (size_t)(blockIdx.x & (NREP - 1)) * 128;
        atomicAdd(&st[tid], sS[tid]);
        atomicAdd(&st[64 + tid], sQ[tid]);
    }
}

// ---------------- BN apply + ReLU; replica-reduce in LDS prologue ----------------
template <int COUT, int CHPN, bool F32OUT, bool BFOUT>
__global__ __launch_bounds__(256) void bn_apply(const float* __restrict__ x,
                                                const float* __restrict__ stats,
                                                const float* __restrict__ g,
                                                const float* __restrict__ b,
                                                float* __restrict__ fout,
                                                short* __restrict__ bfout, int N) {
    constexpr int CW = BFOUT ? CHPN : COUT;
    __shared__ float ssc[COUT];
    __shared__ float ssh[COUT];
    int tid = threadIdx.x;
    if (tid < COUT) {
        float s = 0.f, q = 0.f;
#pragma unroll
        for (int r = 0; r < NREP; ++r) {
            s += stats[r * 128 + tid];
            q += stats[r * 128 + 64 + tid];
        }
        float inv = 1.0f / (float)N;
        float m = s * inv;
        float v = q * inv - m * m;
        float sc = g[tid] / sqrtf(v + BN_EPS);
        ssc[tid] = sc;
        ssh[tid] = b[tid] - m * sc;
    }
    __syncthreads();
    long i = (long)blockIdx.x * 256 + tid;
    if (i >= (long)N * CW) return;
    int c = (int)(i % CW);
    long n = i / CW;
    float y = 0.f;
    if (c < COUT) {
        y = fmaxf(x[n * COUT + c] * ssc[c] + ssh[c], 0.f);
        if (F32OUT) __builtin_nontemporal_store(y, &fout[n * COUT + c]);
    }
    if (BFOUT) bfout[n * CHPN + c] = f2bf(y);
}

// ---------------- host helpers ----------------

template <int CHP, int CO, int K, int SPLITS>
static void conv(const short* fin, const int* rb, const short* wt, float* parts, long pstride,
                 int N, int zrow, hipStream_t stream) {
    constexpr int KS = (K + SPLITS - 1) / SPLITS;
    dim3 grid((N + 127) / 128, SPLITS);
    hipLaunchKernelGGL((sconv_hyb<CHP, CO, KS>), grid, dim3(256), 0, stream, fin, rb, wt, parts,
                       pstride, N, zrow, K);
}

template <int COUT, int SPLITS>
static void reduce(const float* parts, long pstride, float* comb, float* stats, int N,
                   hipStream_t stream) {
    constexpr int RPB = 8 * (256 / COUT);
    int blocks = (N + RPB - 1) / RPB;
    hipLaunchKernelGGL((reduce_stats<COUT, SPLITS>), dim3(blocks), dim3(256), 0, stream, parts,
                       pstride, comb, stats, N);
}

template <int COUT, int CHPN, bool F32OUT, bool BFOUT>
static void apply(const float* preact, const float* stats, const float* g, const float* b,
                  float* fout, short* bfout, int N, hipStream_t stream) {
    constexpr int CW = BFOUT ? CHPN : COUT;
    int blocks = (int)(((long)N * CW + 255) / 256);
    hipLaunchKernelGGL((bn_apply<COUT, CHPN, F32OUT, BFOUT>), dim3(blocks), dim3(256), 0, stream,
                       preact, stats, g, b, fout, bfout, N);
}

extern "C" void kernel_launch(void* const* d_in, const int* in_sizes, int n_in, void* d_out,
                              int out_size, void* d_ws, size_t ws_size, hipStream_t stream) {
    const float* features = (const float*)d_in[0];
    const float* W[14];
    const float* G[14];
    const float* Bb[14];
    for (int i = 0; i < 14; ++i) {
        W[i] = (const float*)d_in[1 + 3 * i];
        G[i] = (const float*)d_in[2 + 3 * i];
        Bb[i] = (const float*)d_in[3 + 3 * i];
    }
    const int* coords0 = (const int*)d_in[43];
    const int* coords1 = (const int*)d_in[44];
    const int* coords2 = (const int*)d_in[45];
    const int* coords3 = (const int*)d_in[46];
    const int* rb0 = (const int*)d_in[47];
    const int* rbc1 = (const int*)d_in[48];
    const int* rb1 = (const int*)d_in[49];
    const int* rbc2 = (const int*)d_in[50];
    const int* rb2 = (const int*)d_in[51];
    const int* rbc3 = (const int*)d_in[52];
    const int* rb3 = (const int*)d_in[53];
    const int* rbc4 = (const int*)d_in[54];

    const int N0 = in_sizes[0] / 4;
    const int N1 = in_sizes[44] / 4;
    const int N2 = in_sizes[45] / 4;
    const int N3 = in_sizes[46] / 4;
    const int N4 = in_sizes[54] / 3;

    float* out = (float*)d_out;
    long off = 0;
    float* xyz0 = out + off; off += (long)N0 * 3;
    float* f0   = out + off; off += (long)N0 * 4;
    float* xyz1 = out + off; off += (long)N1 * 3;
    float* f1   = out + off; off += (long)N1 * 32;
    float* xyz2 = out + off; off += (long)N2 * 3;
    float* f2   = out + off; off += (long)N2 * 64;
    float* xyz3 = out + off; off += (long)N3 * 3;
    float* f3   = out + off; off += (long)N3 * 64;
    float* f4   = out + off;

    long maxN = N0;
    if (N1 > maxN) maxN = N1;
    if (N2 > maxN) maxN = N2;
    if (N3 > maxN) maxN = N3;
    if (N4 > maxN) maxN = N4;
    const int zrow = (int)maxN;
    const long pstrideF = (long)maxN * 64;

    float* comb = (float*)d_ws;                           // maxN*64 fp32 (combined)
    float* parts = comb + pstrideF;                       // 4 * maxN*64 fp32 (partials)
    float* statsBase = parts + 4 * pstrideF;              // 14 * NREP * 128 fp32
    short* bfA = (short*)(statsBase + 14 * NREP * 128);   // (maxN+1)*64 bf16
    short* bfB = bfA + (size_t)(maxN + 1) * 64;           // (maxN+1)*64 bf16
    short* wtBase = bfB + (size_t)(maxN + 1) * 64;        // swizzled bf16 weights

    static const int KK[14] = {27, 27, 27, 27, 27, 27, 27, 27, 27, 27, 27, 27, 27, 3};
    static const int CI[14] = {4, 16, 16, 32, 32, 32, 64, 64, 64, 64, 64, 64, 64, 64};
    static const int CO[14] = {16, 16, 32, 32, 32, 64, 64, 64, 64, 64, 64, 64, 64, 64};
    short* WT[14];
    PrepAll pd;
    {
        size_t o = 0;
        int cum = 0;
        for (int l = 0; l < 14; ++l) {
            WT[l] = wtBase + o;
            int chp = CI[l] <= 32 ? 32 : 64;
            pd.src[l] = W[l];
            pd.dst[l] = WT[l];
            pd.CI[l] = CI[l];
            pd.CO[l] = CO[l];
            pd.CHP[l] = chp;
            pd.cum[l] = cum;
            cum += KK[l] * CO[l] * chp;
            o += (size_t)KK[l] * CO[l] * chp;
        }
        pd.cum[14] = cum;
    }

    int nstats = 14 * NREP * 128;
    hipLaunchKernelGGL(zero_kernel, dim3((nstats + 255) / 256), dim3(256), 0, stream, statsBase,
                       nstats);
    hipLaunchKernelGGL(zero_rows_kernel, dim3(1), dim3(256), 0, stream, bfA, bfB, maxN);
    hipLaunchKernelGGL(prep_all_kernel, dim3((pd.cum[14] + 255) / 256), dim3(256), 0, stream, pd);

    hipLaunchKernelGGL(copy_kernel, dim3((N0 * 4 + 255) / 256), dim3(256), 0, stream, features, f0,
                       N0 * 4);
    hipLaunchKernelGGL(xyz_kernel, dim3((N0 + 255) / 256), dim3(256), 0, stream, coords0, xyz0, N0,
                       0.05f, 0.05f, 0.1f);
    hipLaunchKernelGGL(xyz_kernel, dim3((N1 + 255) / 256), dim3(256), 0, stream, coords1, xyz1, N1,
                       0.1f, 0.1f, 0.2f);
    hipLaunchKernelGGL(xyz_kernel, dim3((N2 + 255) / 256), dim3(256), 0, stream, coords2, xyz2, N2,
                       0.2f, 0.2f, 0.4f);
    hipLaunchKernelGGL(xyz_kernel, dim3((N3 + 255) / 256), dim3(256), 0, stream, coords3, xyz3, N3,
                       0.4f, 0.4f, 0.8f);
    hipLaunchKernelGGL(convert_f0, dim3((N0 * 32 + 255) / 256), dim3(256), 0, stream, features,
                       bfA, N0);

    float* st = statsBase;
#define STAT(l) (st + (size_t)(l)*NREP * 128)
// CHP = INPUT packing (feature rows), CHPO = OUTPUT bf16 packing (next layer's CHP)
#define LAYER(CHP, CHPO, COx, K, SPL, fin, rbp, l, N, fo, bfo, F32O, BFO)                         \
    do {                                                                                          \
        conv<CHP, COx, K, SPL>(fin, rbp, WT[l], parts, pstrideF, N, zrow, stream);                \
        reduce<COx, SPL>(parts, pstrideF, comb, STAT(l), N, stream);                              \
        apply<COx, CHPO, F32O, BFO>((SPL > 1) ? comb : parts, STAT(l), G[l], Bb[l], fo, bfo, N,   \
                                    stream);                                                      \
    } while (0)

    LAYER(32, 32, 16, 27, 4, bfA, rb0, 0, N0, nullptr, bfB, false, true);
    LAYER(32, 32, 16, 27, 4, bfB, rb0, 1, N0, nullptr, bfA, false, true);
    LAYER(32, 32, 32, 27, 4, bfA, rbc1, 2, N1, f1, bfB, true, true);

    LAYER(32, 32, 32, 27, 4, bfB, rb1, 3, N1, nullptr, bfA, false, true);
    LAYER(32, 32, 32, 27, 4, bfA, rb1, 4, N1, nullptr, bfB, false, true);
    LAYER(32, 64, 64, 27, 4, bfB, rbc2, 5, N2, f2, bfA, true, true);

    LAYER(64, 64, 64, 27, 4, bfA, rb2, 6, N2, nullptr, bfB, false, true);
    LAYER(64, 64, 64, 27, 4, bfB, rb2, 7, N2, nullptr, bfA, false, true);
    LAYER(64, 64, 64, 27, 4, bfA, rb2, 8, N2, nullptr, bfB, false, true);
    LAYER(64, 64, 64, 27, 4, bfB, rbc3, 9, N3, f3, bfA, true, true);

    LAYER(64, 64, 64, 27, 4, bfA, rb3, 10, N3, nullptr, bfB, false, true);
    LAYER(64, 64, 64, 27, 4, bfB, rb3, 11, N3, nullptr, bfA, false, true);
    LAYER(64, 64, 64, 27, 4, bfA, rb3, 12, N3, nullptr, bfB, false, true);
    LAYER(64, 64, 64, 3, 1, bfB, rbc4, 13, N4, f4, nullptr, true, false);
#undef LAYER
#undef STAT
}